// Round 11
// baseline (173.322 us; speedup 1.0000x reference)
//
#include <hip/hip_runtime.h>

#define NB 64
#define NN 100
#define DL 32
#define BN (NB * NN)  // 6400

typedef _Float16 f16x8 __attribute__((ext_vector_type(8)));
typedef float f32x4 __attribute__((ext_vector_type(4)));

static __device__ __forceinline__ float lrelu(float x) { return fmaxf(x, 0.1f * x); }
static __device__ __forceinline__ f32x4 ld4(const float* p) { return *(const f32x4*)p; }
static __device__ __forceinline__ float hsum4(f32x4 v) { return v[0] + v[1] + v[2] + v[3]; }

// Fused: h = x@lin_w+lin_b, U/V for step 0 (V stored f16), W1 B-fragment prep.
// Blocks 0..1599: 4 (b,n) rows each. Blocks 1600..1601: PW for step 0/1.
__global__ __launch_bounds__(256) void k_pre(
    const float* __restrict__ x, const float* __restrict__ lw, const float* __restrict__ lb,
    const float* __restrict__ ew0, const float* __restrict__ eb0,
    const float* __restrict__ w1a, const float* __restrict__ w1b,
    float* __restrict__ h, float* __restrict__ U, _Float16* __restrict__ V,
    _Float16* __restrict__ PW) {
    int blk = blockIdx.x;
    int t = threadIdx.x;
    if (blk >= 1600) {  // B-fragment swizzle: PW[step][kt][hf][lane][jj]
        int step = blk - 1600;
        const float* w1 = step ? w1b : w1a;
        _Float16* dst = PW + step * 4096;
#pragma unroll
        for (int u = 0; u < 16; ++u) {
            int idx = t * 16 + u;
            int jj = idx & 7, lane = (idx >> 3) & 63, hf = (idx >> 9) & 1, kt = idx >> 10;
            int c = hf * 32 + (lane >> 4) * 8 + jj;
            int k = kt * 16 + (lane & 15);
            dst[idx] = (_Float16)w1[c * 64 + k];
        }
        return;
    }
    __shared__ float xs[DL];
    __shared__ float hs[4][DL];
    int row0 = blk * 4;
    int b = row0 / NN;  // 4-row group never crosses a batch boundary (100 % 4 == 0)
    if (t < DL) xs[t] = x[b * DL + t];
    __syncthreads();
    if (t < 128) {
        int ni = t >> 5, c = t & 31;
        int n = (row0 + ni) % NN;
        float s = lb[n * DL + c];
#pragma unroll
        for (int cc = 0; cc < DL; ++cc) s += xs[cc] * lw[cc * 3200 + n * DL + c];
        hs[ni][c] = s;
        h[(row0 + ni) * DL + c] = s;
    }
    __syncthreads();
#pragma unroll
    for (int r = 0; r < 2; ++r) {
        int o = r * 256 + t;  // 0..511 : 4 rows x (64 U + 64 V)
        int ni = o >> 7, kw = o & 127;
        int which = kw >> 6, k = kw & 63;
        const float* wp = ew0 + (which ? DL * 64 : 0) + k;
        float s = which ? 0.f : eb0[k];
#pragma unroll
        for (int c = 0; c < DL; ++c) s += hs[ni][c] * wp[c * 64];
        if (which) V[(row0 + ni) * 64 + k] = (_Float16)s;
        else       U[(row0 + ni) * 64 + k] = s;
    }
}

// Per-wave edge+node step, ONE barrier (R7/R10 structure). R10 diagnosis: the
// epilogue's weight stream (w0n 24.6K + w1n 8.2K + wA 16.4K = 49KB) exceeds the
// 32KB L1 -> every wave pays ~250 L2-latency loads it cannot hide at 2.5
// waves/SIMD. v17: stage ALL epilogue weights in LDS under the existing single
// barrier (block-invariant data; column reads are bank = lane%32, 2-way = free).
// LDS 13.3K -> ~61K caps residency at 2 blocks/CU == today's measured ~2.5.
// Kept: no min-waves bound (R4/R5 spill), opaque-pb anti-hoist (R7), packed-f16
// P-build + f16 V (R6), LDS pwl staging (R9), 4-lane dist + ld4 epilogue (R10).
template <int FINAL>
__global__ __launch_bounds__(256) void k_edge(
    const float* __restrict__ h, const float* __restrict__ U, const _Float16* __restrict__ V,
    const float* __restrict__ w0, const _Float16* __restrict__ PW,
    const float* __restrict__ b1,
    const float* __restrict__ w0n, const float* __restrict__ b0n,
    const float* __restrict__ w1n, const float* __restrict__ b1n,
    const float* __restrict__ wA, const float* __restrict__ bA,
    float* __restrict__ hout, float* __restrict__ Uo, _Float16* __restrict__ Vo,
    float* __restrict__ out) {
    __shared__ __align__(16) _Float16 pwl[4096];
    __shared__ float sdist[4][112];
    __shared__ __align__(16) float sxin[4][96];  // [0..31]=h_i, [32..95]=agg
    __shared__ __align__(16) float st0[4][64];
    __shared__ __align__(16) float sh2[4][32];
    __shared__ __align__(16) float swn0[96 * 64];                 // 24.6 KB
    __shared__ __align__(16) float swn1[64 * 32];                 //  8.2 KB
    __shared__ __align__(16) float swa[FINAL ? 96 : 64 * 64];     // 0.4 / 16.4 KB

    int t = threadIdx.x;
    {  // stage W1 B-fragments + ALL epilogue weights once for the whole block
        const f16x8* srcp = (const f16x8*)PW;
        f16x8* dstp = (f16x8*)pwl;
        dstp[t] = srcp[t];
        dstp[t + 256] = srcp[t + 256];
        const f32x4* s0 = (const f32x4*)w0n;
        f32x4* d0 = (f32x4*)swn0;
#pragma unroll
        for (int i = 0; i < 6; ++i) d0[t + i * 256] = s0[t + i * 256];  // 6144 f
        const f32x4* s1 = (const f32x4*)w1n;
        f32x4* d1 = (f32x4*)swn1;
        d1[t] = s1[t];
        d1[t + 256] = s1[t + 256];                                      // 2048 f
        if (FINAL) {
            if (t < 96) swa[t] = wA[t];                                 //   96 f
        } else {
            const f32x4* s2 = (const f32x4*)wA;
            f32x4* d2 = (f32x4*)swa;
#pragma unroll
            for (int i = 0; i < 4; ++i) d2[t + i * 256] = s2[t + i * 256];  // 4096 f
        }
    }
    int w = t >> 6, lane = t & 63, q = lane >> 4, kk = lane & 15;
    int bi = blockIdx.x * 4 + w;
    int b = bi / NN;

    // h_i -> LDS (wave-local; read later via broadcast in the node MLP)
    if (lane < 32) sxin[w][lane] = h[bi * DL + lane];

    // distances: 4 lanes per j (16 j per iter, 7 iters), 32B/lane coalesced,
    // 2-step shfl reduce. All sdist writes complete before the barrier below.
    {
        int g = lane >> 2, r = lane & 3;
        const float* hi = h + bi * DL + r * 8;
        f32x4 hi0 = ld4(hi), hi1 = ld4(hi + 4);
        const float* hb = h + b * NN * DL;
#pragma unroll
        for (int it = 0; it < 7; ++it) {
            int j = it * 16 + g;
            int jc = j < NN ? j : NN - 1;
            const float* hj = hb + jc * DL + r * 8;
            f32x4 d0 = hi0 - ld4(hj);
            f32x4 d1 = hi1 - ld4(hj + 4);
            f32x4 s4 = d0 * d0 + d1 * d1;
            float s = hsum4(s4);
            s += __shfl_xor(s, 1);
            s += __shfl_xor(s, 2);
            if (r == 0) sdist[w][j] = sqrtf(s + 1e-12f);
        }
    }

    int c0 = q * 8;  // this lane's channel base
    // u (U_i + b0 folded) and wd as packed f16 (8 VGPRs each)
    f16x8 ulo, uhi, wdlo, wdhi;
    {
        const float* Up = U + (size_t)bi * 64;
        f32x4 a0 = ld4(Up + c0), a1 = ld4(Up + c0 + 4);
        f32x4 a2 = ld4(Up + 32 + c0), a3 = ld4(Up + 36 + c0);
        const float* wd = w0 + 64 * 64;
        f32x4 d0 = ld4(wd + c0), d1 = ld4(wd + c0 + 4);
        f32x4 d2 = ld4(wd + 32 + c0), d3 = ld4(wd + 36 + c0);
#pragma unroll
        for (int i = 0; i < 4; ++i) {
            ulo[i] = (_Float16)a0[i];  ulo[i + 4] = (_Float16)a1[i];
            uhi[i] = (_Float16)a2[i];  uhi[i + 4] = (_Float16)a3[i];
            wdlo[i] = (_Float16)d0[i]; wdlo[i + 4] = (_Float16)d1[i];
            wdhi[i] = (_Float16)d2[i]; wdhi[i + 4] = (_Float16)d3[i];
        }
    }
    float b1k[4];
#pragma unroll
    for (int kt = 0; kt < 4; ++kt) b1k[kt] = b1[kt * 16 + kk];
    float m6 = (q == 0) ? 1.f : 0.f;  // tile 6: only rows 96..99 (q==0) valid

    const _Float16* Vb = V + (size_t)b * NN * 64;
    // prefetch tile 0 (j = kk < 100, no clamp); V rows are f16
    f16x8 vlo, vhi;
    {
        const _Float16* vr = Vb + kk * 64 + c0;
        vlo = *(const f16x8*)vr;
        vhi = *(const f16x8*)(vr + 32);
    }

    __syncthreads();  // pwl + staged weights ready
    float dj = sdist[w][kk];

    float sacc[4] = {0.f, 0.f, 0.f, 0.f};
    unsigned pb = 0;  // opaque LDS byte-offset: re-defined each jt by the asm nop
#pragma unroll
    for (int jt = 0; jt < 7; ++jt) {
        // P build in packed f16: result is exactly this lane's A-fragments
        _Float16 djh = (_Float16)dj;
        f16x8 dj8;
#pragma unroll
        for (int i = 0; i < 8; ++i) dj8[i] = djh;
        f16x8 A0 = __builtin_elementwise_fma(dj8, wdlo, ulo + vlo);
        f16x8 A1 = __builtin_elementwise_fma(dj8, wdhi, uhi + vhi);
        A0 = __builtin_elementwise_max(A0, (_Float16)0.1f * A0);
        A1 = __builtin_elementwise_max(A1, (_Float16)0.1f * A1);

        if (jt < 6) {  // prefetch next tile into the SAME v regs (in-order issue)
            int j = (jt + 1) * 16 + kk;
            int jc = (jt == 5 && j >= NN) ? NN - 1 : j;
            const _Float16* vr = Vb + jc * 64 + c0;
            vlo = *(const f16x8*)vr;
            vhi = *(const f16x8*)(vr + 32);
            dj = sdist[w][j];
        }
        // Opaque base: compiler cannot CSE/hoist the 8 B-frag ds_reads across
        // jt iterations -> they stay inside this body (peak +8 regs, not +32).
        asm volatile("" : "+v"(pb));
        const _Float16* pB = (const _Float16*)((const char*)pwl + pb);
#pragma unroll
        for (int kt = 0; kt < 4; ++kt) {
            f16x8 B0 = *(const f16x8*)&pB[(kt * 2 + 0) * 512 + lane * 8];
            f16x8 B1 = *(const f16x8*)&pB[(kt * 2 + 1) * 512 + lane * 8];
            f32x4 a = {0.f, 0.f, 0.f, 0.f};
            a = __builtin_amdgcn_mfma_f32_16x16x32_f16(A0, B0, a, 0, 0, 0);
            a = __builtin_amdgcn_mfma_f32_16x16x32_f16(A1, B1, a, 0, 0, 0);
            f32x4 s4 = a + b1k[kt];
            s4 = __builtin_elementwise_max(s4, 0.1f * s4);
            float hs = hsum4(s4);
            sacc[kt] += (jt == 6) ? hs * m6 : hs;  // mask rows j >= 100 on last tile
        }
    }

    // agg[k]: reduce across q groups; col kk -> k = kt*16+kk
    {
        float ag[4];
#pragma unroll
        for (int kt = 0; kt < 4; ++kt) {
            float s = sacc[kt];
            s += __shfl_xor(s, 16);
            s += __shfl_xor(s, 32);
            ag[kt] = s;
        }
        if (lane < 16) {
#pragma unroll
            for (int kt = 0; kt < 4; ++kt) sxin[w][32 + kt * 16 + lane] = ag[kt];
        }
    }

    // node MLP layer 0: lane = output k, LDS weights swn0[c*64+k] (bank=lane%32,
    // 2-way = free); inputs batched as ds_read_b128 via ld4
    {
        float sa = 0.f, sb = 0.f, sc = 0.f, sd = 0.f;
#pragma unroll
        for (int c4 = 0; c4 < 24; ++c4) {
            f32x4 xv = ld4(&sxin[w][c4 * 4]);
            sa += xv[0] * swn0[(c4 * 4 + 0) * 64 + lane];
            sb += xv[1] * swn0[(c4 * 4 + 1) * 64 + lane];
            sc += xv[2] * swn0[(c4 * 4 + 2) * 64 + lane];
            sd += xv[3] * swn0[(c4 * 4 + 3) * 64 + lane];
        }
        st0[w][lane] = lrelu((sa + sb) + (sc + sd) + b0n[lane]);
    }
    // node MLP layer 1: k = lane&31, half p = lane>>5, shfl-combine; ld4 inputs
    {
        int k2 = lane & 31, p = lane >> 5;
        float sa = 0.f, sb = 0.f, sc = 0.f, sd = 0.f;
#pragma unroll
        for (int c4 = 0; c4 < 8; ++c4) {
            f32x4 xv = ld4(&st0[w][p * 32 + c4 * 4]);
            int c = p * 32 + c4 * 4;
            sa += xv[0] * swn1[(c + 0) * DL + k2];
            sb += xv[1] * swn1[(c + 1) * DL + k2];
            sc += xv[2] * swn1[(c + 2) * DL + k2];
            sd += xv[3] * swn1[(c + 3) * DL + k2];
        }
        float s = (sa + sb) + (sc + sd);
        s += __shfl_xor(s, 32);
        if (lane < 32) {
            float hv = lrelu(s + b1n[lane]);
            sh2[w][lane] = hv;
            if (!FINAL) hout[bi * DL + lane] = hv;
        }
    }

    if (FINAL) {
        if (lane < 3) {
            float s = bA[lane];
#pragma unroll
            for (int c4 = 0; c4 < 8; ++c4) {
                f32x4 xv = ld4(&sh2[w][c4 * 4]);
#pragma unroll
                for (int i = 0; i < 4; ++i) s += xv[i] * swa[(c4 * 4 + i) * 3 + lane];
            }
            out[bi * 3 + lane] = tanhf(s);
        }
    } else {  // U/V for the next step (LDS weights, coalesced layout); V stored f16
        float su = bA[lane], sv = 0.f;
#pragma unroll
        for (int c4 = 0; c4 < 8; ++c4) {
            f32x4 xv = ld4(&sh2[w][c4 * 4]);
#pragma unroll
            for (int i = 0; i < 4; ++i) {
                int c = c4 * 4 + i;
                su += xv[i] * swa[c * 64 + lane];
                sv += xv[i] * swa[(DL + c) * 64 + lane];
            }
        }
        Uo[bi * 64 + lane] = su;
        Vo[bi * 64 + lane] = (_Float16)sv;
    }
}

extern "C" void kernel_launch(void* const* d_in, const int* in_sizes, int n_in,
                              void* d_out, int out_size, void* d_ws, size_t ws_size,
                              hipStream_t stream) {
    const float* x     = (const float*)d_in[0];
    const float* lin_w = (const float*)d_in[1];
    const float* lin_b = (const float*)d_in[2];
    const float* ew0[2] = {(const float*)d_in[3],  (const float*)d_in[11]};
    const float* eb0[2] = {(const float*)d_in[4],  (const float*)d_in[12]};
    const float* ew1[2] = {(const float*)d_in[5],  (const float*)d_in[13]};
    const float* eb1[2] = {(const float*)d_in[6],  (const float*)d_in[14]};
    const float* nw0[2] = {(const float*)d_in[7],  (const float*)d_in[15]};
    const float* nb0[2] = {(const float*)d_in[8],  (const float*)d_in[16]};
    const float* nw1[2] = {(const float*)d_in[9],  (const float*)d_in[17]};
    const float* nb1[2] = {(const float*)d_in[10], (const float*)d_in[18]};
    const float* ow = (const float*)d_in[19];
    const float* ob = (const float*)d_in[20];
    float* out = (float*)d_out;

    float* h    = (float*)d_ws;               // 6400 x 32 f32
    float* h2   = h + 204800;                 // 6400 x 32 f32
    float* U    = h2 + 204800;                // 6400 x 64 f32
    float* U2   = U + 409600;                 // 6400 x 64 f32
    _Float16* V  = (_Float16*)(U2 + 409600);  // 6400 x 64 f16
    _Float16* V2 = V + 409600;                // 6400 x 64 f16
    _Float16* PW = V2 + 409600;               // 2 x 4096 f16

    k_pre<<<1602, 256, 0, stream>>>(x, lin_w, lin_b, ew0[0], eb0[0], ew1[0], ew1[1],
                                    h, U, V, PW);
    k_edge<0><<<1600, 256, 0, stream>>>(h, U, V, ew0[0], PW, eb1[0],
                                        nw0[0], nb0[0], nw1[0], nb1[0],
                                        ew0[1], eb0[1], h2, U2, V2, nullptr);
    k_edge<1><<<1600, 256, 0, stream>>>(h2, U2, V2, ew0[1], PW + 4096, eb1[1],
                                        nw0[1], nb0[1], nw1[1], nb1[1],
                                        ow, ob, nullptr, nullptr, nullptr, out);
}

// Round 12
// 158.728 us; speedup vs baseline: 1.0919x; 1.0919x over previous
//
#include <hip/hip_runtime.h>

#define NB 64
#define NN 100
#define DL 32
#define BN (NB * NN)  // 6400

typedef _Float16 f16x8 __attribute__((ext_vector_type(8)));
typedef float f32x4 __attribute__((ext_vector_type(4)));

static __device__ __forceinline__ float lrelu(float x) { return fmaxf(x, 0.1f * x); }
static __device__ __forceinline__ f32x4 ld4(const float* p) { return *(const f32x4*)p; }
static __device__ __forceinline__ float hsum4(f32x4 v) { return v[0] + v[1] + v[2] + v[3]; }

// Fused: h = x@lin_w+lin_b, U/V for step 0 (V stored f16), W1 B-fragment prep.
// Blocks 0..1599: 4 (b,n) rows each. Blocks 1600..1601: PW for step 0/1.
__global__ __launch_bounds__(256) void k_pre(
    const float* __restrict__ x, const float* __restrict__ lw, const float* __restrict__ lb,
    const float* __restrict__ ew0, const float* __restrict__ eb0,
    const float* __restrict__ w1a, const float* __restrict__ w1b,
    float* __restrict__ h, float* __restrict__ U, _Float16* __restrict__ V,
    _Float16* __restrict__ PW) {
    int blk = blockIdx.x;
    int t = threadIdx.x;
    if (blk >= 1600) {  // B-fragment swizzle: PW[step][kt][hf][lane][jj]
        int step = blk - 1600;
        const float* w1 = step ? w1b : w1a;
        _Float16* dst = PW + step * 4096;
#pragma unroll
        for (int u = 0; u < 16; ++u) {
            int idx = t * 16 + u;
            int jj = idx & 7, lane = (idx >> 3) & 63, hf = (idx >> 9) & 1, kt = idx >> 10;
            int c = hf * 32 + (lane >> 4) * 8 + jj;
            int k = kt * 16 + (lane & 15);
            dst[idx] = (_Float16)w1[c * 64 + k];
        }
        return;
    }
    __shared__ float xs[DL];
    __shared__ float hs[4][DL];
    int row0 = blk * 4;
    int b = row0 / NN;  // 4-row group never crosses a batch boundary (100 % 4 == 0)
    if (t < DL) xs[t] = x[b * DL + t];
    __syncthreads();
    if (t < 128) {
        int ni = t >> 5, c = t & 31;
        int n = (row0 + ni) % NN;
        float s = lb[n * DL + c];
#pragma unroll
        for (int cc = 0; cc < DL; ++cc) s += xs[cc] * lw[cc * 3200 + n * DL + c];
        hs[ni][c] = s;
        h[(row0 + ni) * DL + c] = s;
    }
    __syncthreads();
#pragma unroll
    for (int r = 0; r < 2; ++r) {
        int o = r * 256 + t;  // 0..511 : 4 rows x (64 U + 64 V)
        int ni = o >> 7, kw = o & 127;
        int which = kw >> 6, k = kw & 63;
        const float* wp = ew0 + (which ? DL * 64 : 0) + k;
        float s = which ? 0.f : eb0[k];
#pragma unroll
        for (int c = 0; c < DL; ++c) s += hs[ni][c] * wp[c * 64];
        if (which) V[(row0 + ni) * 64 + k] = (_Float16)s;
        else       U[(row0 + ni) * 64 + k] = s;
    }
}

// Per-wave edge+node step, ONE barrier (R10 base -- best bench 161.9us).
// R11 lesson: staging ALL epilogue weights (62KB LDS) capped residency at 2
// blocks/CU and regressed the BENCH total despite better per-dispatch counters;
// rocprof dispatch times are not comparable across rounds (clock state) -- only
// the bench total is ground truth. v19 hybrid: stage ONLY w0n (24.6KB; LDS ->
// ~38K, cap 4 blocks/CU >= measured ~3) so the remaining global set (w1n 8.2K +
// wA 16.4K) fits the 32KB L1. Plus s_setprio(1) around the MFMA cluster
// (independent-wave regime, attn-like: m191 +4-7%).
// Kept: no min-waves bound (R4/R5 spill), opaque-pb anti-hoist (R7), packed-f16
// P-build + f16 V (R6), LDS pwl staging (R9), 4-lane dist + ld4 epilogue (R10).
template <int FINAL>
__global__ __launch_bounds__(256) void k_edge(
    const float* __restrict__ h, const float* __restrict__ U, const _Float16* __restrict__ V,
    const float* __restrict__ w0, const _Float16* __restrict__ PW,
    const float* __restrict__ b1,
    const float* __restrict__ w0n, const float* __restrict__ b0n,
    const float* __restrict__ w1n, const float* __restrict__ b1n,
    const float* __restrict__ wA, const float* __restrict__ bA,
    float* __restrict__ hout, float* __restrict__ Uo, _Float16* __restrict__ Vo,
    float* __restrict__ out) {
    __shared__ __align__(16) _Float16 pwl[4096];
    __shared__ float sdist[4][112];
    __shared__ __align__(16) float sxin[4][96];  // [0..31]=h_i, [32..95]=agg
    __shared__ __align__(16) float st0[4][64];
    __shared__ __align__(16) float sh2[4][32];
    __shared__ __align__(16) float swn0[96 * 64];  // 24.6 KB: node-L0 weights

    int t = threadIdx.x;
    {  // stage W1 B-fragments + node-L0 weights once for the whole block
        const f16x8* srcp = (const f16x8*)PW;
        f16x8* dstp = (f16x8*)pwl;
        dstp[t] = srcp[t];
        dstp[t + 256] = srcp[t + 256];
        const f32x4* s0 = (const f32x4*)w0n;
        f32x4* d0 = (f32x4*)swn0;
#pragma unroll
        for (int i = 0; i < 6; ++i) d0[t + i * 256] = s0[t + i * 256];  // 6144 f
    }
    int w = t >> 6, lane = t & 63, q = lane >> 4, kk = lane & 15;
    int bi = blockIdx.x * 4 + w;
    int b = bi / NN;

    // h_i -> LDS (wave-local; read later via broadcast in the node MLP)
    if (lane < 32) sxin[w][lane] = h[bi * DL + lane];

    // distances: 4 lanes per j (16 j per iter, 7 iters), 32B/lane coalesced,
    // 2-step shfl reduce. All sdist writes complete before the barrier below.
    {
        int g = lane >> 2, r = lane & 3;
        const float* hi = h + bi * DL + r * 8;
        f32x4 hi0 = ld4(hi), hi1 = ld4(hi + 4);
        const float* hb = h + b * NN * DL;
#pragma unroll
        for (int it = 0; it < 7; ++it) {
            int j = it * 16 + g;
            int jc = j < NN ? j : NN - 1;
            const float* hj = hb + jc * DL + r * 8;
            f32x4 d0 = hi0 - ld4(hj);
            f32x4 d1 = hi1 - ld4(hj + 4);
            f32x4 s4 = d0 * d0 + d1 * d1;
            float s = hsum4(s4);
            s += __shfl_xor(s, 1);
            s += __shfl_xor(s, 2);
            if (r == 0) sdist[w][j] = sqrtf(s + 1e-12f);
        }
    }

    int c0 = q * 8;  // this lane's channel base
    // u (U_i + b0 folded) and wd as packed f16 (8 VGPRs each)
    f16x8 ulo, uhi, wdlo, wdhi;
    {
        const float* Up = U + (size_t)bi * 64;
        f32x4 a0 = ld4(Up + c0), a1 = ld4(Up + c0 + 4);
        f32x4 a2 = ld4(Up + 32 + c0), a3 = ld4(Up + 36 + c0);
        const float* wd = w0 + 64 * 64;
        f32x4 d0 = ld4(wd + c0), d1 = ld4(wd + c0 + 4);
        f32x4 d2 = ld4(wd + 32 + c0), d3 = ld4(wd + 36 + c0);
#pragma unroll
        for (int i = 0; i < 4; ++i) {
            ulo[i] = (_Float16)a0[i];  ulo[i + 4] = (_Float16)a1[i];
            uhi[i] = (_Float16)a2[i];  uhi[i + 4] = (_Float16)a3[i];
            wdlo[i] = (_Float16)d0[i]; wdlo[i + 4] = (_Float16)d1[i];
            wdhi[i] = (_Float16)d2[i]; wdhi[i + 4] = (_Float16)d3[i];
        }
    }
    float b1k[4];
#pragma unroll
    for (int kt = 0; kt < 4; ++kt) b1k[kt] = b1[kt * 16 + kk];
    float m6 = (q == 0) ? 1.f : 0.f;  // tile 6: only rows 96..99 (q==0) valid

    const _Float16* Vb = V + (size_t)b * NN * 64;
    // prefetch tile 0 (j = kk < 100, no clamp); V rows are f16
    f16x8 vlo, vhi;
    {
        const _Float16* vr = Vb + kk * 64 + c0;
        vlo = *(const f16x8*)vr;
        vhi = *(const f16x8*)(vr + 32);
    }

    __syncthreads();  // pwl + swn0 ready
    float dj = sdist[w][kk];

    float sacc[4] = {0.f, 0.f, 0.f, 0.f};
    unsigned pb = 0;  // opaque LDS byte-offset: re-defined each jt by the asm nop
#pragma unroll
    for (int jt = 0; jt < 7; ++jt) {
        // P build in packed f16: result is exactly this lane's A-fragments
        _Float16 djh = (_Float16)dj;
        f16x8 dj8;
#pragma unroll
        for (int i = 0; i < 8; ++i) dj8[i] = djh;
        f16x8 A0 = __builtin_elementwise_fma(dj8, wdlo, ulo + vlo);
        f16x8 A1 = __builtin_elementwise_fma(dj8, wdhi, uhi + vhi);
        A0 = __builtin_elementwise_max(A0, (_Float16)0.1f * A0);
        A1 = __builtin_elementwise_max(A1, (_Float16)0.1f * A1);

        if (jt < 6) {  // prefetch next tile into the SAME v regs (in-order issue)
            int j = (jt + 1) * 16 + kk;
            int jc = (jt == 5 && j >= NN) ? NN - 1 : j;
            const _Float16* vr = Vb + jc * 64 + c0;
            vlo = *(const f16x8*)vr;
            vhi = *(const f16x8*)(vr + 32);
            dj = sdist[w][j];
        }
        // Opaque base: compiler cannot CSE/hoist the 8 B-frag ds_reads across
        // jt iterations -> they stay inside this body (peak +8 regs, not +32).
        asm volatile("" : "+v"(pb));
        const _Float16* pB = (const _Float16*)((const char*)pwl + pb);
        __builtin_amdgcn_s_setprio(1);
#pragma unroll
        for (int kt = 0; kt < 4; ++kt) {
            f16x8 B0 = *(const f16x8*)&pB[(kt * 2 + 0) * 512 + lane * 8];
            f16x8 B1 = *(const f16x8*)&pB[(kt * 2 + 1) * 512 + lane * 8];
            f32x4 a = {0.f, 0.f, 0.f, 0.f};
            a = __builtin_amdgcn_mfma_f32_16x16x32_f16(A0, B0, a, 0, 0, 0);
            a = __builtin_amdgcn_mfma_f32_16x16x32_f16(A1, B1, a, 0, 0, 0);
            f32x4 s4 = a + b1k[kt];
            s4 = __builtin_elementwise_max(s4, 0.1f * s4);
            float hs = hsum4(s4);
            sacc[kt] += (jt == 6) ? hs * m6 : hs;  // mask rows j >= 100 on last tile
        }
        __builtin_amdgcn_s_setprio(0);
    }

    // agg[k]: reduce across q groups; col kk -> k = kt*16+kk
    {
        float ag[4];
#pragma unroll
        for (int kt = 0; kt < 4; ++kt) {
            float s = sacc[kt];
            s += __shfl_xor(s, 16);
            s += __shfl_xor(s, 32);
            ag[kt] = s;
        }
        if (lane < 16) {
#pragma unroll
            for (int kt = 0; kt < 4; ++kt) sxin[w][32 + kt * 16 + lane] = ag[kt];
        }
    }

    // node MLP layer 0: lane = output k, LDS weights swn0[c*64+lane] (bank =
    // lane%32, 2-way = free); inputs batched as ds_read_b128 via ld4
    {
        float sa = 0.f, sb = 0.f, sc = 0.f, sd = 0.f;
#pragma unroll
        for (int c4 = 0; c4 < 24; ++c4) {
            f32x4 xv = ld4(&sxin[w][c4 * 4]);
            sa += xv[0] * swn0[(c4 * 4 + 0) * 64 + lane];
            sb += xv[1] * swn0[(c4 * 4 + 1) * 64 + lane];
            sc += xv[2] * swn0[(c4 * 4 + 2) * 64 + lane];
            sd += xv[3] * swn0[(c4 * 4 + 3) * 64 + lane];
        }
        st0[w][lane] = lrelu((sa + sb) + (sc + sd) + b0n[lane]);
    }
    // node MLP layer 1: k = lane&31, half p = lane>>5, shfl-combine; ld4 inputs
    // (w1n stays global: with w0n staged, w1n+wA = 24.6KB fits L1)
    {
        int k2 = lane & 31, p = lane >> 5;
        float sa = 0.f, sb = 0.f, sc = 0.f, sd = 0.f;
#pragma unroll
        for (int c4 = 0; c4 < 8; ++c4) {
            f32x4 xv = ld4(&st0[w][p * 32 + c4 * 4]);
            int c = p * 32 + c4 * 4;
            sa += xv[0] * w1n[(c + 0) * DL + k2];
            sb += xv[1] * w1n[(c + 1) * DL + k2];
            sc += xv[2] * w1n[(c + 2) * DL + k2];
            sd += xv[3] * w1n[(c + 3) * DL + k2];
        }
        float s = (sa + sb) + (sc + sd);
        s += __shfl_xor(s, 32);
        if (lane < 32) {
            float hv = lrelu(s + b1n[lane]);
            sh2[w][lane] = hv;
            if (!FINAL) hout[bi * DL + lane] = hv;
        }
    }

    if (FINAL) {
        if (lane < 3) {
            float s = bA[lane];
#pragma unroll
            for (int c4 = 0; c4 < 8; ++c4) {
                f32x4 xv = ld4(&sh2[w][c4 * 4]);
#pragma unroll
                for (int i = 0; i < 4; ++i) s += xv[i] * wA[(c4 * 4 + i) * 3 + lane];
            }
            out[bi * 3 + lane] = tanhf(s);
        }
    } else {  // U/V for the next step (coalesced ew0 layout); V stored f16; ld4 inputs
        float su = bA[lane], sv = 0.f;
#pragma unroll
        for (int c4 = 0; c4 < 8; ++c4) {
            f32x4 xv = ld4(&sh2[w][c4 * 4]);
#pragma unroll
            for (int i = 0; i < 4; ++i) {
                int c = c4 * 4 + i;
                su += xv[i] * wA[c * 64 + lane];
                sv += xv[i] * wA[(DL + c) * 64 + lane];
            }
        }
        Uo[bi * 64 + lane] = su;
        Vo[bi * 64 + lane] = (_Float16)sv;
    }
}

extern "C" void kernel_launch(void* const* d_in, const int* in_sizes, int n_in,
                              void* d_out, int out_size, void* d_ws, size_t ws_size,
                              hipStream_t stream) {
    const float* x     = (const float*)d_in[0];
    const float* lin_w = (const float*)d_in[1];
    const float* lin_b = (const float*)d_in[2];
    const float* ew0[2] = {(const float*)d_in[3],  (const float*)d_in[11]};
    const float* eb0[2] = {(const float*)d_in[4],  (const float*)d_in[12]};
    const float* ew1[2] = {(const float*)d_in[5],  (const float*)d_in[13]};
    const float* eb1[2] = {(const float*)d_in[6],  (const float*)d_in[14]};
    const float* nw0[2] = {(const float*)d_in[7],  (const float*)d_in[15]};
    const float* nb0[2] = {(const float*)d_in[8],  (const float*)d_in[16]};
    const float* nw1[2] = {(const float*)d_in[9],  (const float*)d_in[17]};
    const float* nb1[2] = {(const float*)d_in[10], (const float*)d_in[18]};
    const float* ow = (const float*)d_in[19];
    const float* ob = (const float*)d_in[20];
    float* out = (float*)d_out;

    float* h    = (float*)d_ws;               // 6400 x 32 f32
    float* h2   = h + 204800;                 // 6400 x 32 f32
    float* U    = h2 + 204800;                // 6400 x 64 f32
    float* U2   = U + 409600;                 // 6400 x 64 f32
    _Float16* V  = (_Float16*)(U2 + 409600);  // 6400 x 64 f16
    _Float16* V2 = V + 409600;                // 6400 x 64 f16
    _Float16* PW = V2 + 409600;               // 2 x 4096 f16

    k_pre<<<1602, 256, 0, stream>>>(x, lin_w, lin_b, ew0[0], eb0[0], ew1[0], ew1[1],
                                    h, U, V, PW);
    k_edge<0><<<1600, 256, 0, stream>>>(h, U, V, ew0[0], PW, eb1[0],
                                        nw0[0], nb0[0], nw1[0], nb1[0],
                                        ew0[1], eb0[1], h2, U2, V2, nullptr);
    k_edge<1><<<1600, 256, 0, stream>>>(h2, U2, V2, ew0[1], PW + 4096, eb1[1],
                                        nw0[1], nb0[1], nw1[1], nb1[1],
                                        ow, ob, nullptr, nullptr, nullptr, out);
}